// Round 3
// baseline (35724.402 us; speedup 1.0000x reference)
//
#include <hip/hip_runtime.h>

// Problem constants (fixed by the reference): T=512, B=64, I=256, H=512.
#define T_DIM 512
#define B_DIM 64
#define I_DIM 256
#define H_DIM 512
#define BH_DIM (B_DIM * H_DIM)   // 32768

// ---------------------------------------------------------------------------
// Stage 1: xw[t,b,h] = dot(x[t,b,:], Wih[h,:]) + bias_ih[h] + bias_hh[h]
// GEMM, M = T*B = 32768, N = H = 512, K = I = 256 (NT). Unchanged from R1.
// ---------------------------------------------------------------------------
__global__ __launch_bounds__(256) void xw_gemm(
    const float* __restrict__ x, const float* __restrict__ wih,
    const float* __restrict__ bih, const float* __restrict__ bhh,
    float* __restrict__ out) {
  __shared__ float xs[32][68];  // [k][m], padded row
  __shared__ float ws[32][68];  // [k][n]

  const int m_base = blockIdx.y * 64;
  const int n_base = blockIdx.x * 64;
  const int tid = threadIdx.x;
  const int tn = tid & 15;
  const int tm = tid >> 4;
  const int lr = tid >> 3;
  const int lk = (tid & 7) << 2;

  float acc[4][4];
#pragma unroll
  for (int i = 0; i < 4; i++)
#pragma unroll
    for (int j = 0; j < 4; j++) acc[i][j] = 0.f;

  for (int kc = 0; kc < I_DIM; kc += 32) {
    __syncthreads();
    const float4 xv0 = *(const float4*)&x[(size_t)(m_base + lr) * I_DIM + kc + lk];
    const float4 xv1 = *(const float4*)&x[(size_t)(m_base + lr + 32) * I_DIM + kc + lk];
    const float4 wv0 = *(const float4*)&wih[(size_t)(n_base + lr) * I_DIM + kc + lk];
    const float4 wv1 = *(const float4*)&wih[(size_t)(n_base + lr + 32) * I_DIM + kc + lk];
    xs[lk + 0][lr] = xv0.x; xs[lk + 1][lr] = xv0.y;
    xs[lk + 2][lr] = xv0.z; xs[lk + 3][lr] = xv0.w;
    xs[lk + 0][lr + 32] = xv1.x; xs[lk + 1][lr + 32] = xv1.y;
    xs[lk + 2][lr + 32] = xv1.z; xs[lk + 3][lr + 32] = xv1.w;
    ws[lk + 0][lr] = wv0.x; ws[lk + 1][lr] = wv0.y;
    ws[lk + 2][lr] = wv0.z; ws[lk + 3][lr] = wv0.w;
    ws[lk + 0][lr + 32] = wv1.x; ws[lk + 1][lr + 32] = wv1.y;
    ws[lk + 2][lr + 32] = wv1.z; ws[lk + 3][lr + 32] = wv1.w;
    __syncthreads();

#pragma unroll
    for (int k = 0; k < 32; k++) {
      const float4 a = *(const float4*)&xs[k][tm * 4];
      const float4 b = *(const float4*)&ws[k][tn * 4];
      acc[0][0] = fmaf(a.x, b.x, acc[0][0]); acc[0][1] = fmaf(a.x, b.y, acc[0][1]);
      acc[0][2] = fmaf(a.x, b.z, acc[0][2]); acc[0][3] = fmaf(a.x, b.w, acc[0][3]);
      acc[1][0] = fmaf(a.y, b.x, acc[1][0]); acc[1][1] = fmaf(a.y, b.y, acc[1][1]);
      acc[1][2] = fmaf(a.y, b.z, acc[1][2]); acc[1][3] = fmaf(a.y, b.w, acc[1][3]);
      acc[2][0] = fmaf(a.z, b.x, acc[2][0]); acc[2][1] = fmaf(a.z, b.y, acc[2][1]);
      acc[2][2] = fmaf(a.z, b.z, acc[2][2]); acc[2][3] = fmaf(a.z, b.w, acc[2][3]);
      acc[3][0] = fmaf(a.w, b.x, acc[3][0]); acc[3][1] = fmaf(a.w, b.y, acc[3][1]);
      acc[3][2] = fmaf(a.w, b.z, acc[3][2]); acc[3][3] = fmaf(a.w, b.w, acc[3][3]);
    }
  }

  const int n0 = n_base + tn * 4;
  float4 bias;
  bias.x = bih[n0 + 0] + bhh[n0 + 0];
  bias.y = bih[n0 + 1] + bhh[n0 + 1];
  bias.z = bih[n0 + 2] + bhh[n0 + 2];
  bias.w = bih[n0 + 3] + bhh[n0 + 3];
#pragma unroll
  for (int mi = 0; mi < 4; mi++) {
    const int m = m_base + tm * 4 + mi;
    float4 o;
    o.x = acc[mi][0] + bias.x; o.y = acc[mi][1] + bias.y;
    o.z = acc[mi][2] + bias.z; o.w = acc[mi][3] + bias.w;
    *(float4*)&out[(size_t)m * H_DIM + n0] = o;
  }
}

// ---------------------------------------------------------------------------
// Stage 2 (round-3 rewrite): W_hh entirely in REGISTERS, loaded once.
// Grid: 256 blocks = 64 batches x 4 row-chunks (blockIdx = rb*64 + b, so the
// 4 partners of a batch share blockIdx mod 8 -> likely same XCD; correctness
// does not depend on it). 1024 threads, 64 W-VGPRs/thread ->
// __launch_bounds__(1024,4) caps 128 VGPR -> exactly 1 block/CU -> all 256
// blocks co-resident (spin-sync is deadlock-free by capacity).
//
// Thread (rg = tid>>5, cg = tid&31) owns rows j0..j0+3 (j0 = rb*128 + rg*4)
// x float4-columns {cg, 32+cg, 64+cg, 96+cg} (k-interleaved so LDS reads are
// 32 consecutive float4s per half-wave: conflict-free, upper half broadcasts).
//
// h exchange: out[t] IS h_t. After writing its chunk, a block does an
// agent-scope release store of t to its flag; partners acquire-spin.
// Flags live in d_ws: 0xAA poison = negative int -> blocks until t=0 stored.
// ---------------------------------------------------------------------------
__global__ __launch_bounds__(1024, 4) void rnn_scan_mb(
    const float* __restrict__ whh, float* __restrict__ out,
    int* __restrict__ flags) {
  __shared__ __align__(16) float hbuf[2][H_DIM];

  const int b   = blockIdx.x & 63;
  const int rb  = blockIdx.x >> 6;       // row-chunk 0..3
  const int tid = threadIdx.x;
  const int rg  = tid >> 5;              // 0..31
  const int cg  = tid & 31;              // 0..31
  const int j0  = rb * 128 + rg * 4;     // first of my 4 rows

  // ---- load W chunk into registers (one time; coalesced per half-wave) ----
  float4 w[4][4];
#pragma unroll
  for (int r = 0; r < 4; r++) {
    const float4* wr = (const float4*)(whh + (size_t)(j0 + r) * H_DIM);
#pragma unroll
    for (int i = 0; i < 4; i++) w[r][i] = wr[i * 32 + cg];
  }

  float* __restrict__ outb = out + (size_t)b * H_DIM;  // t-stride = BH_DIM

  // ---- t = 0: h_0 = relu(xw_0), write in place, publish flag=0 ----
  float4 hlast = make_float4(0.f, 0.f, 0.f, 0.f);
  if (cg == 0) {
    float4 xw = *(float4*)&outb[j0];
    hlast.x = fmaxf(xw.x, 0.f); hlast.y = fmaxf(xw.y, 0.f);
    hlast.z = fmaxf(xw.z, 0.f); hlast.w = fmaxf(xw.w, 0.f);
    *(float4*)&outb[j0] = hlast;
  }
  __syncthreads();  // barrier drains vmcnt: all h_0 stores done
  if (tid == 0) {
    __threadfence();
    __hip_atomic_store(&flags[blockIdx.x], 0, __ATOMIC_RELEASE,
                       __HIP_MEMORY_SCOPE_AGENT);
  }

  // ---- main scan ----
  for (int t = 1; t < T_DIM; t++) {
    float* o_t = outb + (size_t)t * BH_DIM;
    const float* o_p = o_t - BH_DIM;  // out[t-1] == h_{t-1}

    // xw_t for my rows: written by stage-1 GEMM, safe to read pre-spin
    float4 xw = make_float4(0.f, 0.f, 0.f, 0.f);
    if (cg == 0) xw = *(const float4*)&o_t[j0];

    // wait for the 3 partner chunks of h_{t-1}
    if (tid < 4 && tid != rb) {
      while (__hip_atomic_load(&flags[tid * 64 + b], __ATOMIC_ACQUIRE,
                               __HIP_MEMORY_SCOPE_AGENT) < t - 1) {}
    }
    __syncthreads();
    __threadfence();  // acquire side: discard stale cached h lines

    // stage h_{t-1} (512 floats) into LDS, double-buffered
    float* hb = hbuf[t & 1];
    if (tid < 128) ((float4*)hb)[tid] = ((const float4*)o_p)[tid];
    __syncthreads();

    // compute: 4 rows x 64 k-values per thread
    float a0 = 0.f, a1 = 0.f, a2 = 0.f, a3 = 0.f;
#pragma unroll
    for (int i = 0; i < 4; i++) {
      const float4 hv = ((const float4*)hb)[i * 32 + cg];
      a0 = fmaf(w[0][i].x, hv.x, a0); a0 = fmaf(w[0][i].y, hv.y, a0);
      a0 = fmaf(w[0][i].z, hv.z, a0); a0 = fmaf(w[0][i].w, hv.w, a0);
      a1 = fmaf(w[1][i].x, hv.x, a1); a1 = fmaf(w[1][i].y, hv.y, a1);
      a1 = fmaf(w[1][i].z, hv.z, a1); a1 = fmaf(w[1][i].w, hv.w, a1);
      a2 = fmaf(w[2][i].x, hv.x, a2); a2 = fmaf(w[2][i].y, hv.y, a2);
      a2 = fmaf(w[2][i].z, hv.z, a2); a2 = fmaf(w[2][i].w, hv.w, a2);
      a3 = fmaf(w[3][i].x, hv.x, a3); a3 = fmaf(w[3][i].y, hv.y, a3);
      a3 = fmaf(w[3][i].z, hv.z, a3); a3 = fmaf(w[3][i].w, hv.w, a3);
    }
    // reduce across the 32 cg lanes (xor masks stay within the 32-lane half)
#pragma unroll
    for (int m = 16; m >= 1; m >>= 1) {
      a0 += __shfl_xor(a0, m, 64);
      a1 += __shfl_xor(a1, m, 64);
      a2 += __shfl_xor(a2, m, 64);
      a3 += __shfl_xor(a3, m, 64);
    }

    if (cg == 0) {
      float4 h;
      h.x = fmaxf(a0 + xw.x, 0.f);
      h.y = fmaxf(a1 + xw.y, 0.f);
      h.z = fmaxf(a2 + xw.z, 0.f);
      h.w = fmaxf(a3 + xw.w, 0.f);
      *(float4*)&o_t[j0] = h;  // output[t,b,j0..j0+3] == h_t
      hlast = h;
    }
    __syncthreads();  // all h_t stores of this block done (vmcnt drained)
    if (tid == 0) {
      __threadfence();
      __hip_atomic_store(&flags[blockIdx.x], t, __ATOMIC_RELEASE,
                         __HIP_MEMORY_SCOPE_AGENT);
    }
  }

  // h_final = h_{T-1}
  if (cg == 0) {
    float* fin = out + (size_t)T_DIM * BH_DIM + (size_t)b * H_DIM;
    *(float4*)&fin[j0] = hlast;
  }
}

extern "C" void kernel_launch(void* const* d_in, const int* in_sizes, int n_in,
                              void* d_out, int out_size, void* d_ws, size_t ws_size,
                              hipStream_t stream) {
  const float* x   = (const float*)d_in[0];  // [T,B,I]
  const float* wih = (const float*)d_in[1];  // [H,I]
  const float* whh = (const float*)d_in[2];  // [H,H]
  const float* bih = (const float*)d_in[3];  // [H]
  const float* bhh = (const float*)d_in[4];  // [H]
  float* out = (float*)d_out;                // [T,B,H] output ++ [B,H] h_final
  int* flags = (int*)d_ws;                   // 256 ints; 0xAA poison < 0

  dim3 g1(H_DIM / 64, (T_DIM * B_DIM) / 64);  // (8, 512) tiles
  xw_gemm<<<g1, 256, 0, stream>>>(x, wih, bih, bhh, out);

  rnn_scan_mb<<<256, 1024, 0, stream>>>(whh, out, flags);
}

// Round 4
// 1649.921 us; speedup vs baseline: 21.6522x; 21.6522x over previous
//
#include <hip/hip_runtime.h>

// Problem constants (fixed by the reference): T=512, B=64, I=256, H=512.
#define T_DIM 512
#define B_DIM 64
#define I_DIM 256
#define H_DIM 512
#define BH_DIM (B_DIM * H_DIM)   // 32768

// ---------------------------------------------------------------------------
// Stage 1: xw[t,b,h] = dot(x[t,b,:], Wih[h,:]) + bias_ih[h] + bias_hh[h]
// GEMM, M = T*B = 32768, N = H = 512, K = I = 256 (NT). Unchanged from R1.
// ---------------------------------------------------------------------------
__global__ __launch_bounds__(256) void xw_gemm(
    const float* __restrict__ x, const float* __restrict__ wih,
    const float* __restrict__ bih, const float* __restrict__ bhh,
    float* __restrict__ out) {
  __shared__ float xs[32][68];  // [k][m], padded row
  __shared__ float ws[32][68];  // [k][n]

  const int m_base = blockIdx.y * 64;
  const int n_base = blockIdx.x * 64;
  const int tid = threadIdx.x;
  const int tn = tid & 15;
  const int tm = tid >> 4;
  const int lr = tid >> 3;
  const int lk = (tid & 7) << 2;

  float acc[4][4];
#pragma unroll
  for (int i = 0; i < 4; i++)
#pragma unroll
    for (int j = 0; j < 4; j++) acc[i][j] = 0.f;

  for (int kc = 0; kc < I_DIM; kc += 32) {
    __syncthreads();
    const float4 xv0 = *(const float4*)&x[(size_t)(m_base + lr) * I_DIM + kc + lk];
    const float4 xv1 = *(const float4*)&x[(size_t)(m_base + lr + 32) * I_DIM + kc + lk];
    const float4 wv0 = *(const float4*)&wih[(size_t)(n_base + lr) * I_DIM + kc + lk];
    const float4 wv1 = *(const float4*)&wih[(size_t)(n_base + lr + 32) * I_DIM + kc + lk];
    xs[lk + 0][lr] = xv0.x; xs[lk + 1][lr] = xv0.y;
    xs[lk + 2][lr] = xv0.z; xs[lk + 3][lr] = xv0.w;
    xs[lk + 0][lr + 32] = xv1.x; xs[lk + 1][lr + 32] = xv1.y;
    xs[lk + 2][lr + 32] = xv1.z; xs[lk + 3][lr + 32] = xv1.w;
    ws[lk + 0][lr] = wv0.x; ws[lk + 1][lr] = wv0.y;
    ws[lk + 2][lr] = wv0.z; ws[lk + 3][lr] = wv0.w;
    ws[lk + 0][lr + 32] = wv1.x; ws[lk + 1][lr + 32] = wv1.y;
    ws[lk + 2][lr + 32] = wv1.z; ws[lk + 3][lr + 32] = wv1.w;
    __syncthreads();

#pragma unroll
    for (int k = 0; k < 32; k++) {
      const float4 a = *(const float4*)&xs[k][tm * 4];
      const float4 b = *(const float4*)&ws[k][tn * 4];
      acc[0][0] = fmaf(a.x, b.x, acc[0][0]); acc[0][1] = fmaf(a.x, b.y, acc[0][1]);
      acc[0][2] = fmaf(a.x, b.z, acc[0][2]); acc[0][3] = fmaf(a.x, b.w, acc[0][3]);
      acc[1][0] = fmaf(a.y, b.x, acc[1][0]); acc[1][1] = fmaf(a.y, b.y, acc[1][1]);
      acc[1][2] = fmaf(a.y, b.z, acc[1][2]); acc[1][3] = fmaf(a.y, b.w, acc[1][3]);
      acc[2][0] = fmaf(a.z, b.x, acc[2][0]); acc[2][1] = fmaf(a.z, b.y, acc[2][1]);
      acc[2][2] = fmaf(a.z, b.z, acc[2][2]); acc[2][3] = fmaf(a.z, b.w, acc[2][3]);
      acc[3][0] = fmaf(a.w, b.x, acc[3][0]); acc[3][1] = fmaf(a.w, b.y, acc[3][1]);
      acc[3][2] = fmaf(a.w, b.z, acc[3][2]); acc[3][3] = fmaf(a.w, b.w, acc[3][3]);
    }
  }

  const int n0 = n_base + tn * 4;
  float4 bias;
  bias.x = bih[n0 + 0] + bhh[n0 + 0];
  bias.y = bih[n0 + 1] + bhh[n0 + 1];
  bias.z = bih[n0 + 2] + bhh[n0 + 2];
  bias.w = bih[n0 + 3] + bhh[n0 + 3];
#pragma unroll
  for (int mi = 0; mi < 4; mi++) {
    const int m = m_base + tm * 4 + mi;
    float4 o;
    o.x = acc[mi][0] + bias.x; o.y = acc[mi][1] + bias.y;
    o.z = acc[mi][2] + bias.z; o.w = acc[mi][3] + bias.w;
    *(float4*)&out[(size_t)m * H_DIM + n0] = o;
  }
}

// ---------------------------------------------------------------------------
// Stage 2 (round-4): W_hh in registers (as R3) + FENCE-FREE tagged exchange.
// R3's killer was __threadfence/acquire at agent scope -> buffer_wbl2 /
// buffer_inv (whole-L2 writeback/invalidate) every step. Fix: each exchanged
// h element is ONE 8-byte relaxed agent-scope atomic word packing
// (tag = t in high 32b, fp32 bits in low 32b). Tag+payload in the same word
// -> no ordering requirement -> no fences, just sc1 load/store at the
// coherence point (works cross-XCD).
//
// Staging in d_ws: stage[parity][b][j], 2*64*512*8 = 512 KB. Parity double
// buffer makes the protocol ABA-safe: block A can only overwrite a slot
// (tag t+2 over t) after consuming partners' tag-(t+1) words, which
// post-date (their barrier) their reads of tag-t; so a consumer spinning
// for EXACT tag t-1 can never miss it. Poison 0xAAAAAAAA != any tag.
// Deadlock-free: 256 blocks always co-resident (1024 thr, <=128 VGPR).
//
// Grid 256 = 64 batches x 4 row-chunks of 128 rows. Thread (rg=tid>>5,
// cg=tid&31) owns rows j0..j0+3 (j0 = rb*128+rg*4) x float4-cols
// {cg, 32+cg, 64+cg, 96+cg}. 64 W floats/thread in VGPRs.
// ---------------------------------------------------------------------------
__global__ __launch_bounds__(1024, 4) void rnn_scan_tag(
    const float* __restrict__ whh, float* __restrict__ out,
    unsigned long long* __restrict__ stage) {
  __shared__ __align__(16) float hbuf[2][H_DIM];

  const int b   = blockIdx.x & 63;
  const int rb  = blockIdx.x >> 6;       // row-chunk 0..3
  const int tid = threadIdx.x;
  const int rg  = tid >> 5;              // 0..31
  const int cg  = tid & 31;              // 0..31
  const int j0  = rb * 128 + rg * 4;     // first of my 4 rows

  // my spin target: one partner element (threads 0..383), skipping own chunk
  const int pj = (tid < rb * 128) ? tid : tid + 128;

  // ---- load W chunk into registers (once) ----
  float4 w[4][4];
#pragma unroll
  for (int r = 0; r < 4; r++) {
    const float4* wr = (const float4*)(whh + (size_t)(j0 + r) * H_DIM);
#pragma unroll
    for (int i = 0; i < 4; i++) w[r][i] = wr[i * 32 + cg];
  }

  float* __restrict__ outb = out + (size_t)b * H_DIM;  // t-stride = BH_DIM
  unsigned long long* __restrict__ stg_b0 = stage + (size_t)b * H_DIM;
  unsigned long long* __restrict__ stg_b1 = stage + (size_t)(64 + b) * H_DIM;

  // ---- t = 0: h_0 = relu(xw_0); publish tagged words (tag 0, parity 0) ----
  float4 hlast = make_float4(0.f, 0.f, 0.f, 0.f);
  if (cg == 0) {
    float4 xw = *(float4*)&outb[j0];
    float4 h;
    h.x = fmaxf(xw.x, 0.f); h.y = fmaxf(xw.y, 0.f);
    h.z = fmaxf(xw.z, 0.f); h.w = fmaxf(xw.w, 0.f);
#pragma unroll
    for (int q = 0; q < 4; q++) {
      union { float f; unsigned int u; } cv; cv.f = (&h.x)[q];
      __hip_atomic_store(&stg_b0[j0 + q], (unsigned long long)cv.u,
                         __ATOMIC_RELAXED, __HIP_MEMORY_SCOPE_AGENT);
    }
    *(float4*)&outb[j0] = h;
    *(float4*)&hbuf[0][j0] = h;
    hlast = h;
  }

  // ---- main scan ----
  for (int t = 1; t < T_DIM; t++) {
    float* o_t = outb + (size_t)t * BH_DIM;
    const int p = (t - 1) & 1;           // parity of h_{t-1}
    float* hb = hbuf[p];

    // (a) spin-collect the 384 partner elements of h_{t-1} into LDS
    if (tid < 384) {
      unsigned long long* slot = (p ? stg_b1 : stg_b0) + pj;
      const unsigned int want = (unsigned int)(t - 1);
      unsigned long long v;
      do {
        v = __hip_atomic_load(slot, __ATOMIC_RELAXED, __HIP_MEMORY_SCOPE_AGENT);
      } while ((unsigned int)(v >> 32) != want);
      union { unsigned int u; float f; } cv; cv.u = (unsigned int)v;
      hb[pj] = cv.f;
    }

    // (b) prefetch xw_t for my rows (plain load; written by stage-1 GEMM)
    float4 xw = make_float4(0.f, 0.f, 0.f, 0.f);
    if (cg == 0) xw = *(const float4*)&o_t[j0];

    __syncthreads();  // LDS h_{t-1} complete; also isolates hbuf parity reuse

    // (d) compute: 4 rows x 64 k-values per thread
    float a0 = 0.f, a1 = 0.f, a2 = 0.f, a3 = 0.f;
#pragma unroll
    for (int i = 0; i < 4; i++) {
      const float4 hv = ((const float4*)hb)[i * 32 + cg];
      a0 = fmaf(w[0][i].x, hv.x, a0); a0 = fmaf(w[0][i].y, hv.y, a0);
      a0 = fmaf(w[0][i].z, hv.z, a0); a0 = fmaf(w[0][i].w, hv.w, a0);
      a1 = fmaf(w[1][i].x, hv.x, a1); a1 = fmaf(w[1][i].y, hv.y, a1);
      a1 = fmaf(w[1][i].z, hv.z, a1); a1 = fmaf(w[1][i].w, hv.w, a1);
      a2 = fmaf(w[2][i].x, hv.x, a2); a2 = fmaf(w[2][i].y, hv.y, a2);
      a2 = fmaf(w[2][i].z, hv.z, a2); a2 = fmaf(w[2][i].w, hv.w, a2);
      a3 = fmaf(w[3][i].x, hv.x, a3); a3 = fmaf(w[3][i].y, hv.y, a3);
      a3 = fmaf(w[3][i].z, hv.z, a3); a3 = fmaf(w[3][i].w, hv.w, a3);
    }
#pragma unroll
    for (int m = 16; m >= 1; m >>= 1) {
      a0 += __shfl_xor(a0, m, 64);
      a1 += __shfl_xor(a1, m, 64);
      a2 += __shfl_xor(a2, m, 64);
      a3 += __shfl_xor(a3, m, 64);
    }

    // (e) produce h_t: publish tagged words FIRST (shortest critical path)
    if (cg == 0) {
      float4 h;
      h.x = fmaxf(a0 + xw.x, 0.f);
      h.y = fmaxf(a1 + xw.y, 0.f);
      h.z = fmaxf(a2 + xw.z, 0.f);
      h.w = fmaxf(a3 + xw.w, 0.f);
      unsigned long long* sb = ((t & 1) ? stg_b1 : stg_b0) + j0;
      const unsigned long long tag = (unsigned long long)(unsigned int)t << 32;
#pragma unroll
      for (int q = 0; q < 4; q++) {
        union { float f; unsigned int u; } cv; cv.f = (&h.x)[q];
        __hip_atomic_store(&sb[q], tag | cv.u,
                           __ATOMIC_RELAXED, __HIP_MEMORY_SCOPE_AGENT);
      }
      *(float4*)&o_t[j0] = h;          // output[t,b,j0..3] (plain store)
      *(float4*)&hbuf[t & 1][j0] = h;  // own rows for next step
      hlast = h;
    }
  }

  // h_final = h_{T-1}
  if (cg == 0) {
    float* fin = out + (size_t)T_DIM * BH_DIM + (size_t)b * H_DIM;
    *(float4*)&fin[j0] = hlast;
  }
}

extern "C" void kernel_launch(void* const* d_in, const int* in_sizes, int n_in,
                              void* d_out, int out_size, void* d_ws, size_t ws_size,
                              hipStream_t stream) {
  const float* x   = (const float*)d_in[0];  // [T,B,I]
  const float* wih = (const float*)d_in[1];  // [H,I]
  const float* whh = (const float*)d_in[2];  // [H,H]
  const float* bih = (const float*)d_in[3];  // [H]
  const float* bhh = (const float*)d_in[4];  // [H]
  float* out = (float*)d_out;                // [T,B,H] output ++ [B,H] h_final
  // staging: 2 parities x 64 batches x 512 tagged 8B words = 512 KB
  unsigned long long* stage = (unsigned long long*)d_ws;

  dim3 g1(H_DIM / 64, (T_DIM * B_DIM) / 64);  // (8, 512) tiles
  xw_gemm<<<g1, 256, 0, stream>>>(x, wih, bih, bhh, out);

  rnn_scan_tag<<<256, 1024, 0, stream>>>(whh, out, stage);
}

// Round 5
// 1037.271 us; speedup vs baseline: 34.4407x; 1.5906x over previous
//
#include <hip/hip_runtime.h>

// Problem constants (fixed by the reference): T=512, B=64, I=256, H=512.
#define T_DIM 512
#define B_DIM 64
#define I_DIM 256
#define H_DIM 512
#define BH_DIM (B_DIM * H_DIM)   // 32768

// ---------------------------------------------------------------------------
// Stage 1: xw[t,b,h] = dot(x[t,b,:], Wih[h,:]) + bias_ih[h] + bias_hh[h]
// GEMM, M = T*B = 32768, N = H = 512, K = I = 256 (NT). Unchanged from R1.
// ---------------------------------------------------------------------------
__global__ __launch_bounds__(256) void xw_gemm(
    const float* __restrict__ x, const float* __restrict__ wih,
    const float* __restrict__ bih, const float* __restrict__ bhh,
    float* __restrict__ out) {
  __shared__ float xs[32][68];  // [k][m], padded row
  __shared__ float ws[32][68];  // [k][n]

  const int m_base = blockIdx.y * 64;
  const int n_base = blockIdx.x * 64;
  const int tid = threadIdx.x;
  const int tn = tid & 15;
  const int tm = tid >> 4;
  const int lr = tid >> 3;
  const int lk = (tid & 7) << 2;

  float acc[4][4];
#pragma unroll
  for (int i = 0; i < 4; i++)
#pragma unroll
    for (int j = 0; j < 4; j++) acc[i][j] = 0.f;

  for (int kc = 0; kc < I_DIM; kc += 32) {
    __syncthreads();
    const float4 xv0 = *(const float4*)&x[(size_t)(m_base + lr) * I_DIM + kc + lk];
    const float4 xv1 = *(const float4*)&x[(size_t)(m_base + lr + 32) * I_DIM + kc + lk];
    const float4 wv0 = *(const float4*)&wih[(size_t)(n_base + lr) * I_DIM + kc + lk];
    const float4 wv1 = *(const float4*)&wih[(size_t)(n_base + lr + 32) * I_DIM + kc + lk];
    xs[lk + 0][lr] = xv0.x; xs[lk + 1][lr] = xv0.y;
    xs[lk + 2][lr] = xv0.z; xs[lk + 3][lr] = xv0.w;
    xs[lk + 0][lr + 32] = xv1.x; xs[lk + 1][lr + 32] = xv1.y;
    xs[lk + 2][lr + 32] = xv1.z; xs[lk + 3][lr + 32] = xv1.w;
    ws[lk + 0][lr] = wv0.x; ws[lk + 1][lr] = wv0.y;
    ws[lk + 2][lr] = wv0.z; ws[lk + 3][lr] = wv0.w;
    ws[lk + 0][lr + 32] = wv1.x; ws[lk + 1][lr + 32] = wv1.y;
    ws[lk + 2][lr + 32] = wv1.z; ws[lk + 3][lr + 32] = wv1.w;
    __syncthreads();

#pragma unroll
    for (int k = 0; k < 32; k++) {
      const float4 a = *(const float4*)&xs[k][tm * 4];
      const float4 b = *(const float4*)&ws[k][tn * 4];
      acc[0][0] = fmaf(a.x, b.x, acc[0][0]); acc[0][1] = fmaf(a.x, b.y, acc[0][1]);
      acc[0][2] = fmaf(a.x, b.z, acc[0][2]); acc[0][3] = fmaf(a.x, b.w, acc[0][3]);
      acc[1][0] = fmaf(a.y, b.x, acc[1][0]); acc[1][1] = fmaf(a.y, b.y, acc[1][1]);
      acc[1][2] = fmaf(a.y, b.z, acc[1][2]); acc[1][3] = fmaf(a.y, b.w, acc[1][3]);
      acc[2][0] = fmaf(a.z, b.x, acc[2][0]); acc[2][1] = fmaf(a.z, b.y, acc[2][1]);
      acc[2][2] = fmaf(a.z, b.z, acc[2][2]); acc[2][3] = fmaf(a.z, b.w, acc[2][3]);
      acc[3][0] = fmaf(a.w, b.x, acc[3][0]); acc[3][1] = fmaf(a.w, b.y, acc[3][1]);
      acc[3][2] = fmaf(a.w, b.z, acc[3][2]); acc[3][3] = fmaf(a.w, b.w, acc[3][3]);
    }
  }

  const int n0 = n_base + tn * 4;
  float4 bias;
  bias.x = bih[n0 + 0] + bhh[n0 + 0];
  bias.y = bih[n0 + 1] + bhh[n0 + 1];
  bias.z = bih[n0 + 2] + bhh[n0 + 2];
  bias.w = bih[n0 + 3] + bhh[n0 + 3];
#pragma unroll
  for (int mi = 0; mi < 4; mi++) {
    const int m = m_base + tm * 4 + mi;
    float4 o;
    o.x = acc[mi][0] + bias.x; o.y = acc[mi][1] + bias.y;
    o.z = acc[mi][2] + bias.z; o.w = acc[mi][3] + bias.w;
    *(float4*)&out[(size_t)m * H_DIM + n0] = o;
  }
}

// ---------------------------------------------------------------------------
// Stage 2 (round-5): tagged fence-free exchange (as R4) with latency fixes.
// R4 diagnosis: VGPR_Count=52 < 64 W floats => compiler pushed W to AGPRs
// under the (1024,4)=128-VGPR cap (per-use v_accvgpr_read tax); publishes
// were 4 serialized stores from 2 lanes/wave; 16-wave barrier.
// Fixes: 512 threads + __launch_bounds__(512,2) -> 256-VGPR budget, W
// (4 rows x 8 float4 = 128 VGPR) stays architectural; publish/relu/xw-load
// done by 4 lanes per row-group (16 active lanes/wave, 16 CONTIGUOUS rows
// -> one coalesced wave-instruction, no serialization); 8-wave barrier.
//
// Protocol (unchanged): stage[parity][b][j] 8B words packing (tag=t, fp32).
// Tag+payload in one relaxed agent-scope atomic word -> no fences. Parity
// double-buffer is ABA-safe; poison 0xAA.. != any tag in [0,512).
// Deadlock-free: 256 blocks x 512thr @ <=256 VGPR -> 1 block/CU, all
// co-resident.
//
// Grid 256 = 4 row-chunks x 64 batches. Thread (rg=tid>>4, cg=tid&15) owns
// rows j0..j0+3 (j0 = rb*128+rg*4) x float4-cols {i*16+cg : i=0..7}.
// ---------------------------------------------------------------------------
__global__ __launch_bounds__(512, 2) void rnn_scan_tag2(
    const float* __restrict__ whh, float* __restrict__ out,
    unsigned long long* __restrict__ stage) {
  __shared__ __align__(16) float hbuf[2][H_DIM];

  const int b   = blockIdx.x & 63;
  const int rb  = blockIdx.x >> 6;       // row-chunk 0..3
  const int tid = threadIdx.x;           // 0..511
  const int rg  = tid >> 4;              // 0..31
  const int cg  = tid & 15;              // 0..15
  const int j0  = rb * 128 + rg * 4;     // first of my 4 rows

  // my spin target: one partner element (threads 0..383), skipping own chunk
  const int pj = (tid < rb * 128) ? tid : tid + 128;

  // ---- load W chunk into registers (once): 4 rows x 8 float4 = 128 VGPR ----
  float4 w[4][8];
#pragma unroll
  for (int r = 0; r < 4; r++) {
    const float4* wr = (const float4*)(whh + (size_t)(j0 + r) * H_DIM);
#pragma unroll
    for (int i = 0; i < 8; i++) w[r][i] = wr[i * 16 + cg];
  }

  float* __restrict__ outb = out + (size_t)b * H_DIM;  // t-stride = BH_DIM
  unsigned long long* __restrict__ stg0 = stage + (size_t)b * H_DIM;
  unsigned long long* __restrict__ stg1 = stage + (size_t)(64 + b) * H_DIM;

  // ---- t = 0: h_0 = relu(xw_0); publish (tag 0, parity 0) ----
  float hlast = 0.f;  // publishing lanes: my row's latest h value
  if (cg < 4) {
    const int j = j0 + cg;  // 16 contiguous rows per wave
    float v = fmaxf(outb[j], 0.f);
    union { float f; unsigned int u; } cv; cv.f = v;
    __hip_atomic_store(&stg0[j], (unsigned long long)cv.u,
                       __ATOMIC_RELAXED, __HIP_MEMORY_SCOPE_AGENT);
    outb[j] = v;
    hbuf[0][j] = v;
    hlast = v;
  }

  // ---- main scan ----
  for (int t = 1; t < T_DIM; t++) {
    const int p = (t - 1) & 1;           // parity of h_{t-1}
    float* hb = hbuf[p];
    float* o_t = outb + (size_t)t * BH_DIM;

    // prefetch xw_t (4B/lane, 64B/wave coalesced) -- overlaps the poll below
    float xw = 0.f;
    if (cg < 4) xw = o_t[j0 + cg];

    // spin-collect the 384 partner elements of h_{t-1} into LDS
    if (tid < 384) {
      unsigned long long* slot = (p ? stg1 : stg0) + pj;
      const unsigned int want = (unsigned int)(t - 1);
      unsigned long long v;
      do {
        v = __hip_atomic_load(slot, __ATOMIC_RELAXED, __HIP_MEMORY_SCOPE_AGENT);
      } while ((unsigned int)(v >> 32) != want);
      union { unsigned int u; float f; } cv; cv.u = (unsigned int)v;
      hb[pj] = cv.f;
    }

    __syncthreads();  // LDS h_{t-1} complete (single barrier per step)

    // compute: 4 rows x 8 float4 per thread (W in architectural VGPRs)
    float a0 = 0.f, a1 = 0.f, a2 = 0.f, a3 = 0.f;
#pragma unroll
    for (int i = 0; i < 8; i++) {
      const float4 hv = ((const float4*)hb)[i * 16 + cg];
      a0 = fmaf(w[0][i].x, hv.x, a0); a0 = fmaf(w[0][i].y, hv.y, a0);
      a0 = fmaf(w[0][i].z, hv.z, a0); a0 = fmaf(w[0][i].w, hv.w, a0);
      a1 = fmaf(w[1][i].x, hv.x, a1); a1 = fmaf(w[1][i].y, hv.y, a1);
      a1 = fmaf(w[1][i].z, hv.z, a1); a1 = fmaf(w[1][i].w, hv.w, a1);
      a2 = fmaf(w[2][i].x, hv.x, a2); a2 = fmaf(w[2][i].y, hv.y, a2);
      a2 = fmaf(w[2][i].z, hv.z, a2); a2 = fmaf(w[2][i].w, hv.w, a2);
      a3 = fmaf(w[3][i].x, hv.x, a3); a3 = fmaf(w[3][i].y, hv.y, a3);
      a3 = fmaf(w[3][i].z, hv.z, a3); a3 = fmaf(w[3][i].w, hv.w, a3);
    }
    // butterfly over the 16 cg lanes: every lane ends with all 4 row sums
#pragma unroll
    for (int m = 1; m <= 8; m <<= 1) {
      a0 += __shfl_xor(a0, m, 64);
      a1 += __shfl_xor(a1, m, 64);
      a2 += __shfl_xor(a2, m, 64);
      a3 += __shfl_xor(a3, m, 64);
    }

    // publish h_t: lanes cg<4 each own one row -> 16 contiguous tagged words
    // per wave, issued in ONE wave-instruction (no per-lane serialization)
    if (cg < 4) {
      const float acc = (cg == 0) ? a0 : (cg == 1) ? a1 : (cg == 2) ? a2 : a3;
      const float h = fmaxf(acc + xw, 0.f);
      const int j = j0 + cg;
      union { float f; unsigned int u; } cv; cv.f = h;
      const unsigned long long tag = (unsigned long long)(unsigned int)t << 32;
      unsigned long long* sb = (t & 1) ? stg1 : stg0;
      __hip_atomic_store(&sb[j], tag | cv.u,
                         __ATOMIC_RELAXED, __HIP_MEMORY_SCOPE_AGENT);
      o_t[j] = h;            // output[t,b,j] (plain store, off critical path)
      hbuf[t & 1][j] = h;    // own rows for next step
      hlast = h;
    }
  }

  // h_final = h_{T-1}
  if (cg < 4) {
    out[(size_t)T_DIM * BH_DIM + (size_t)b * H_DIM + j0 + cg] = hlast;
  }
}

extern "C" void kernel_launch(void* const* d_in, const int* in_sizes, int n_in,
                              void* d_out, int out_size, void* d_ws, size_t ws_size,
                              hipStream_t stream) {
  const float* x   = (const float*)d_in[0];  // [T,B,I]
  const float* wih = (const float*)d_in[1];  // [H,I]
  const float* whh = (const float*)d_in[2];  // [H,H]
  const float* bih = (const float*)d_in[3];  // [H]
  const float* bhh = (const float*)d_in[4];  // [H]
  float* out = (float*)d_out;                // [T,B,H] output ++ [B,H] h_final
  // staging: 2 parities x 64 batches x 512 tagged 8B words = 512 KB
  unsigned long long* stage = (unsigned long long*)d_ws;

  dim3 g1(H_DIM / 64, (T_DIM * B_DIM) / 64);  // (8, 512) tiles
  xw_gemm<<<g1, 256, 0, stream>>>(x, wih, bih, bhh, out);

  rnn_scan_tag2<<<256, 512, 0, stream>>>(whh, out, stage);
}

// Round 6
// 939.110 us; speedup vs baseline: 38.0407x; 1.1045x over previous
//
#include <hip/hip_runtime.h>

// Problem constants (fixed by the reference): T=512, B=64, I=256, H=512.
#define T_DIM 512
#define B_DIM 64
#define I_DIM 256
#define H_DIM 512
#define BH_DIM (B_DIM * H_DIM)   // 32768

// ---------------------------------------------------------------------------
// Round-6: single fused kernel. 256 blocks = 4 row-chunks x 64 batches,
// 512 threads, 1 block/CU (LDS 135 KB forces it -> co-residency guaranteed).
//
// Per block:
//   - W_hh chunk (128 rows x 512) in registers: w[4][8] float4 / thread.
//   - W_ih chunk (128 rows x 256) in LDS (128 KB), loaded once.
//   - x_t (256 floats) prefetched distance-2 into a triple-buffered LDS slot.
// Per step t:
//   A. ih-matvec b0..b3 = W_ih . x_t  (LDS only, no h dependence) -- runs
//      BEFORE the poll, hiding the publish->detect L3 round trip.
//   B. poll partners' tagged h_{t-1} words into hbuf (R5 protocol: 8-byte
//      relaxed agent-scope words packing (tag=t, fp32); parity double-buffer
//      is ABA-safe; no fences).
//   C. barrier; store x_{t+2} prefetch to LDS.
//   D. hh-fma a0..a3 over hbuf; acc = a+b; 16-lane butterfly.
//   E. lanes cg<4 publish: h = relu(acc + bias) -> stage (tagged), out, hbuf.
//
// Thread map (as R5): rg = tid>>4 (0..31), cg = tid&15; rows j0..j0+3
// (j0 = rb*128 + rg*4); hh cols = float4 idx {i*16+cg, i=0..7};
// ih cols = float4 idx {i*16+cg, i=0..3}. All LDS b128 reads have
// c mod 8 == cg mod 8 -> uniform over bank quads -> conflict-free
// (R5 measured SQ_LDS_BANK_CONFLICT = 0 with this pattern).
// ---------------------------------------------------------------------------
__global__ __launch_bounds__(512, 2) void rnn_fused(
    const float* __restrict__ x, const float* __restrict__ wih,
    const float* __restrict__ whh, const float* __restrict__ bih,
    const float* __restrict__ bhh, float* __restrict__ out,
    unsigned long long* __restrict__ stage) {
  __shared__ __align__(16) float4 wihs4[128 * 64];  // 128 KB: my W_ih rows
  __shared__ __align__(16) float hbuf[2][H_DIM];    // 4 KB: h double buffer
  __shared__ __align__(16) float4 xbuf4[3 * 64];    // 3 KB: x_t triple buffer

  const int b   = blockIdx.x & 63;
  const int rb  = blockIdx.x >> 6;       // row-chunk 0..3
  const int tid = threadIdx.x;           // 0..511
  const int rg  = tid >> 4;              // 0..31
  const int cg  = tid & 15;              // 0..15
  const int j0  = rb * 128 + rg * 4;     // first of my 4 rows

  // spin target: one partner element each for threads 0..383 (skip own chunk)
  const int pj = (tid < rb * 128) ? tid : tid + 128;

  // ---- W_hh chunk -> registers (once) ----
  float4 w[4][8];
#pragma unroll
  for (int r = 0; r < 4; r++) {
    const float4* wr = (const float4*)(whh + (size_t)(j0 + r) * H_DIM);
#pragma unroll
    for (int i = 0; i < 8; i++) w[r][i] = wr[i * 16 + cg];
  }

  // ---- W_ih chunk -> LDS (once; coalesced: linear float4 index) ----
  {
    const float4* wg = (const float4*)(wih + (size_t)rb * 128 * I_DIM);
#pragma unroll
    for (int q = 0; q < 16; q++) {
      const int idx = q * 512 + tid;  // 0..8191 = row*64 + c4
      wihs4[idx] = wg[idx];
    }
  }

  // ---- x_0, x_1 preload ----
  const float4* xg = (const float4*)x;  // idx = (t*B_DIM + b)*64 + c4
  if (tid < 64) {
    xbuf4[0 * 64 + tid] = xg[((size_t)0 * B_DIM + b) * 64 + tid];
    xbuf4[1 * 64 + tid] = xg[((size_t)1 * B_DIM + b) * 64 + tid];
  }

  // ---- bias for publishing lanes ----
  float bias = 0.f;
  if (cg < 4) bias = bih[j0 + cg] + bhh[j0 + cg];

  float* __restrict__ outb = out + (size_t)b * H_DIM;  // t-stride = BH_DIM
  unsigned long long* __restrict__ stg0 = stage + (size_t)b * H_DIM;
  unsigned long long* __restrict__ stg1 = stage + (size_t)(64 + b) * H_DIM;

  __syncthreads();  // W_ih, x0, x1 staged

  float hlast = 0.f;

  // ---- t = 0: h_0 = relu(W_ih x_0 + bias); publish (tag 0, parity 0) ----
  {
    float b0 = 0.f, b1 = 0.f, b2 = 0.f, b3 = 0.f;
    const float4* xb = &xbuf4[0];
    const float4* wr = &wihs4[(rg * 4) * 64];
#pragma unroll
    for (int i = 0; i < 4; i++) {
      const float4 xv = xb[i * 16 + cg];
      const float4 q0 = wr[0 * 64 + i * 16 + cg];
      const float4 q1 = wr[1 * 64 + i * 16 + cg];
      const float4 q2 = wr[2 * 64 + i * 16 + cg];
      const float4 q3 = wr[3 * 64 + i * 16 + cg];
      b0 = fmaf(q0.x, xv.x, b0); b0 = fmaf(q0.y, xv.y, b0);
      b0 = fmaf(q0.z, xv.z, b0); b0 = fmaf(q0.w, xv.w, b0);
      b1 = fmaf(q1.x, xv.x, b1); b1 = fmaf(q1.y, xv.y, b1);
      b1 = fmaf(q1.z, xv.z, b1); b1 = fmaf(q1.w, xv.w, b1);
      b2 = fmaf(q2.x, xv.x, b2); b2 = fmaf(q2.y, xv.y, b2);
      b2 = fmaf(q2.z, xv.z, b2); b2 = fmaf(q2.w, xv.w, b2);
      b3 = fmaf(q3.x, xv.x, b3); b3 = fmaf(q3.y, xv.y, b3);
      b3 = fmaf(q3.z, xv.z, b3); b3 = fmaf(q3.w, xv.w, b3);
    }
#pragma unroll
    for (int m = 1; m <= 8; m <<= 1) {
      b0 += __shfl_xor(b0, m, 64);
      b1 += __shfl_xor(b1, m, 64);
      b2 += __shfl_xor(b2, m, 64);
      b3 += __shfl_xor(b3, m, 64);
    }
    if (cg < 4) {
      const float acc = (cg == 0) ? b0 : (cg == 1) ? b1 : (cg == 2) ? b2 : b3;
      const float h = fmaxf(acc + bias, 0.f);
      const int j = j0 + cg;
      union { float f; unsigned int u; } cv; cv.f = h;
      __hip_atomic_store(&stg0[j], (unsigned long long)cv.u,
                         __ATOMIC_RELAXED, __HIP_MEMORY_SCOPE_AGENT);
      outb[j] = h;
      hbuf[0][j] = h;
      hlast = h;
    }
    // prefetch x_2 -> slot 2 (slot has no prior readers)
    if (tid < 64) {
      xbuf4[2 * 64 + tid] = xg[((size_t)2 * B_DIM + b) * 64 + tid];
    }
  }

  // ---- main scan ----
  for (int t = 1; t < T_DIM; t++) {
    const int p = (t - 1) & 1;  // parity of h_{t-1}
    float* hb = hbuf[p];
    float* o_t = outb + (size_t)t * BH_DIM;

    // A. ih-matvec on x_t (no h dependence; overlaps partners' publish->L3)
    float b0 = 0.f, b1 = 0.f, b2 = 0.f, b3 = 0.f;
    {
      const float4* xb = &xbuf4[(t % 3) * 64];
      const float4* wr = &wihs4[(rg * 4) * 64];
#pragma unroll
      for (int i = 0; i < 4; i++) {
        const float4 xv = xb[i * 16 + cg];
        const float4 q0 = wr[0 * 64 + i * 16 + cg];
        const float4 q1 = wr[1 * 64 + i * 16 + cg];
        const float4 q2 = wr[2 * 64 + i * 16 + cg];
        const float4 q3 = wr[3 * 64 + i * 16 + cg];
        b0 = fmaf(q0.x, xv.x, b0); b0 = fmaf(q0.y, xv.y, b0);
        b0 = fmaf(q0.z, xv.z, b0); b0 = fmaf(q0.w, xv.w, b0);
        b1 = fmaf(q1.x, xv.x, b1); b1 = fmaf(q1.y, xv.y, b1);
        b1 = fmaf(q1.z, xv.z, b1); b1 = fmaf(q1.w, xv.w, b1);
        b2 = fmaf(q2.x, xv.x, b2); b2 = fmaf(q2.y, xv.y, b2);
        b2 = fmaf(q2.z, xv.z, b2); b2 = fmaf(q2.w, xv.w, b2);
        b3 = fmaf(q3.x, xv.x, b3); b3 = fmaf(q3.y, xv.y, b3);
        b3 = fmaf(q3.z, xv.z, b3); b3 = fmaf(q3.w, xv.w, b3);
      }
    }

    // issue x_{t+2} global load early (latency off-path)
    float4 xpf = make_float4(0.f, 0.f, 0.f, 0.f);
    const bool do_pf = (tid < 64) && (t + 2 < T_DIM);
    if (do_pf) xpf = xg[((size_t)(t + 2) * B_DIM + b) * 64 + tid];

    // B. spin-collect the 384 partner elements of h_{t-1} into LDS
    if (tid < 384) {
      unsigned long long* slot = (p ? stg1 : stg0) + pj;
      const unsigned int want = (unsigned int)(t - 1);
      unsigned long long v;
      do {
        v = __hip_atomic_load(slot, __ATOMIC_RELAXED, __HIP_MEMORY_SCOPE_AGENT);
      } while ((unsigned int)(v >> 32) != want);
      union { unsigned int u; float f; } cv; cv.u = (unsigned int)v;
      hb[pj] = cv.f;
    }

    __syncthreads();  // h_{t-1} complete in LDS (single barrier per step)

    // C. commit x_{t+2} to its slot (readers are 2 barriers away)
    if (do_pf) xbuf4[((t + 2) % 3) * 64 + tid] = xpf;

    // D. hh-fma: 4 rows x 8 float4 per thread (W_hh in regs/AGPRs)
    float a0 = b0, a1 = b1, a2 = b2, a3 = b3;
#pragma unroll
    for (int i = 0; i < 8; i++) {
      const float4 hv = ((const float4*)hb)[i * 16 + cg];
      a0 = fmaf(w[0][i].x, hv.x, a0); a0 = fmaf(w[0][i].y, hv.y, a0);
      a0 = fmaf(w[0][i].z, hv.z, a0); a0 = fmaf(w[0][i].w, hv.w, a0);
      a1 = fmaf(w[1][i].x, hv.x, a1); a1 = fmaf(w[1][i].y, hv.y, a1);
      a1 = fmaf(w[1][i].z, hv.z, a1); a1 = fmaf(w[1][i].w, hv.w, a1);
      a2 = fmaf(w[2][i].x, hv.x, a2); a2 = fmaf(w[2][i].y, hv.y, a2);
      a2 = fmaf(w[2][i].z, hv.z, a2); a2 = fmaf(w[2][i].w, hv.w, a2);
      a3 = fmaf(w[3][i].x, hv.x, a3); a3 = fmaf(w[3][i].y, hv.y, a3);
      a3 = fmaf(w[3][i].z, hv.z, a3); a3 = fmaf(w[3][i].w, hv.w, a3);
    }
#pragma unroll
    for (int m = 1; m <= 8; m <<= 1) {
      a0 += __shfl_xor(a0, m, 64);
      a1 += __shfl_xor(a1, m, 64);
      a2 += __shfl_xor(a2, m, 64);
      a3 += __shfl_xor(a3, m, 64);
    }

    // E. publish h_t (16 contiguous tagged words per wave, one instruction)
    if (cg < 4) {
      const float acc = (cg == 0) ? a0 : (cg == 1) ? a1 : (cg == 2) ? a2 : a3;
      const float h = fmaxf(acc + bias, 0.f);
      const int j = j0 + cg;
      union { float f; unsigned int u; } cv; cv.f = h;
      const unsigned long long tag = (unsigned long long)(unsigned int)t << 32;
      unsigned long long* sb = (t & 1) ? stg1 : stg0;
      __hip_atomic_store(&sb[j], tag | cv.u,
                         __ATOMIC_RELAXED, __HIP_MEMORY_SCOPE_AGENT);
      o_t[j] = h;            // output[t,b,j]
      hbuf[t & 1][j] = h;    // own rows for next step
      hlast = h;
    }
  }

  // h_final = h_{T-1}
  if (cg < 4) {
    out[(size_t)T_DIM * BH_DIM + (size_t)b * H_DIM + j0 + cg] = hlast;
  }
}

extern "C" void kernel_launch(void* const* d_in, const int* in_sizes, int n_in,
                              void* d_out, int out_size, void* d_ws, size_t ws_size,
                              hipStream_t stream) {
  const float* x   = (const float*)d_in[0];  // [T,B,I]
  const float* wih = (const float*)d_in[1];  // [H,I]
  const float* whh = (const float*)d_in[2];  // [H,H]
  const float* bih = (const float*)d_in[3];  // [H]
  const float* bhh = (const float*)d_in[4];  // [H]
  float* out = (float*)d_out;                // [T,B,H] output ++ [B,H] h_final
  // staging: 2 parities x 64 batches x 512 tagged 8B words = 512 KB
  unsigned long long* stage = (unsigned long long*)d_ws;

  rnn_fused<<<256, 512, 0, stream>>>(x, wih, whh, bih, bhh, out, stage);
}